// Round 3
// baseline (127.341 us; speedup 1.0000x reference)
//
#include <hip/hip_runtime.h>

#define I_FEAT 256
#define O_FEAT 512
#define NSEG   8
#define KDIM   (I_FEAT * NSEG)   // 2048
#define KTOT   (2 * KDIM)        // 4096 (A-part || bias-part)

typedef _Float16 half8   __attribute__((ext_vector_type(8)));
typedef float    floatx4 __attribute__((ext_vector_type(4)));
typedef uint32_t uintx4  __attribute__((ext_vector_type(4)));

// ---------------- Kernel 1: LayerNorm + segment meta ----------------
// meta[row][i] = (seg << 16) | f16bits(xn).  Block = 256 thr = 2 rows.
__global__ __launch_bounds__(256) void ln_meta(
    const float* __restrict__ x,
    const float* __restrict__ gamma,
    const float* __restrict__ beta,
    uint32_t* __restrict__ meta_g,
    int Bn)
{
    __shared__ float s_psum[4];
    __shared__ float s_psq[4];

    const int tid  = threadIdx.x;
    const int row0 = blockIdx.x * 2;
    const int wave = tid >> 6;
    const int lr   = tid >> 7;        // 0/1: which of the 2 rows
    const int lt   = tid & 127;
    const int row  = row0 + lr;

    float v0 = 0.f, v1 = 0.f;
    if (row < Bn) {
        const float* xr = x + (size_t)row * I_FEAT;
        v0 = xr[lt];
        v1 = xr[lt + 128];
    }
    float sum = v0 + v1;
    float sq  = v0 * v0 + v1 * v1;
    #pragma unroll
    for (int d = 32; d > 0; d >>= 1) {
        sum += __shfl_down(sum, d);
        sq  += __shfl_down(sq, d);
    }
    if ((tid & 63) == 0) { s_psum[wave] = sum; s_psq[wave] = sq; }
    __syncthreads();
    if (row >= Bn) return;

    const float fsum = s_psum[2 * lr] + s_psum[2 * lr + 1];
    const float fsq  = s_psq[2 * lr]  + s_psq[2 * lr + 1];
    const float mu   = fsum * (1.0f / I_FEAT);
    const float var  = fsq * (1.0f / I_FEAT) - mu * mu;
    const float rs   = rsqrtf(var + 1e-5f);

    uint32_t* mr = meta_g + (size_t)row * I_FEAT;
    #pragma unroll
    for (int h = 0; h < 2; ++h) {
        const int f = lt + h * 128;
        const float v = h ? v1 : v0;
        float xn = (v - mu) * rs * gamma[f] + beta[f];
        float fi = (xn + 1.0f) * 4.0f;    // (xn - GRID_MIN)/STEP, exact in fp32
        int seg = (int)fi;                 // trunc == jnp astype(int32)
        seg = seg < 0 ? 0 : (seg > NSEG - 1 ? NSEG - 1 : seg);
        _Float16 hx = (_Float16)xn;
        uint32_t hb = (uint32_t)__builtin_bit_cast(unsigned short, hx);
        mr[f] = ((uint32_t)seg << 16) | hb;
    }
}

// ---------------- Kernel 2: transpose-pack weights ----------------
// WT[o][k] (f16), k<2048 -> Aw[k][o], k>=2048 -> Bw[k-2048][o].
// 64x64 tiles; grid (O/64, K/64... g-tiles, part)
__global__ __launch_bounds__(256) void pack_wt(
    const float* __restrict__ Aw,
    const float* __restrict__ Bw,
    unsigned short* __restrict__ WT)
{
    __shared__ _Float16 T[64][72];
    const int t  = threadIdx.x;
    const int o0 = blockIdx.x * 64;
    const int g0 = blockIdx.y * 64;
    const float* src = blockIdx.z ? Bw : Aw;
    const int zoff = blockIdx.z ? KDIM : 0;

    // phase 1: read 64(g) x 64(o) fp32 tile, convert f16 -> LDS
    #pragma unroll
    for (int s = 0; s < 4; ++s) {
        int e = s * 1024 + t * 4;
        int r = e >> 6, c = e & 63;
        const float4 v = *(const float4*)(src + (size_t)(g0 + r) * O_FEAT + o0 + c);
        T[r][c + 0] = (_Float16)v.x; T[r][c + 1] = (_Float16)v.y;
        T[r][c + 2] = (_Float16)v.z; T[r][c + 3] = (_Float16)v.w;
    }
    __syncthreads();

    // phase 2: thread emits 16 g-contiguous f16 of one o-row
    const int ol = t >> 2, gc = t & 3;
    unsigned short tmp[16];
    #pragma unroll
    for (int j = 0; j < 16; ++j)
        tmp[j] = __builtin_bit_cast(unsigned short, T[gc * 16 + j][ol]);
    unsigned short* dst = WT + (size_t)(o0 + ol) * KTOT + zoff + g0 + gc * 16;
    *(uint4*)dst       = *(uint4*)&tmp[0];
    *((uint4*)dst + 1) = *(uint4*)&tmp[8];
}

// ---------------- Kernel 3: meta-driven MFMA GEMM ----------------
// C[64m x 64n] per block; 4 waves = 2x2 of 32x32; mfma_f32_16x16x32_f16.
// A-frag built in-register from meta (one-hot over the 8-aligned k-window);
// B-frag from LDS-staged WT slab (XOR cell swizzle, uniform bank colors).
__global__ __launch_bounds__(256, 1) void kan_mfma(
    const uint32_t* __restrict__ meta_g,     // [Bn][256]
    const unsigned short* __restrict__ WT,   // [512][4096] f16
    float* __restrict__ out,
    int Bn)
{
    __shared__ uint32_t       meta_s[64 * 257];   // [m][i], stride 257 (bank-spread)
    __shared__ unsigned short wt_s[64 * 256];     // [n][k-slab 256], 16B-cell swizzled

    const int t      = threadIdx.x;
    const int ob     = blockIdx.x * 64;
    const int rb     = blockIdx.y * 64;
    const int wave   = t >> 6, lane = t & 63;
    const int wm     = wave >> 1, wn = wave & 1;
    const int lane16 = lane & 15, quad = lane >> 4;

    // load meta tile 64 x 256 -> LDS
    #pragma unroll
    for (int s = 0; s < 16; ++s) {
        int e = s * 1024 + t * 4;
        int r = e >> 8, c = e & 255;
        uint32_t m0 = 0, m1 = 0, m2 = 0, m3 = 0;
        int grow = rb + r;
        if (grow < Bn) {
            const uintx4 v = *(const uintx4*)(meta_g + (size_t)grow * I_FEAT + c);
            m0 = v[0]; m1 = v[1]; m2 = v[2]; m3 = v[3];
        }
        uint32_t* p = meta_s + r * 257 + c;
        p[0] = m0; p[1] = m1; p[2] = m2; p[3] = m3;
    }

    floatx4 acc[2][2] = {};

    const int srow = t >> 5;   // staging: row within 8-row group
    const int scol = t & 31;   // staging: 16B cell 0..31
    uint4 stg[8];
    #pragma unroll
    for (int p = 0; p < 8; ++p) {
        int n = p * 8 + srow;
        stg[p] = *(const uint4*)(WT + (size_t)(ob + n) * KTOT + scol * 8);
    }
    __syncthreads();           // meta_s ready
    #pragma unroll
    for (int p = 0; p < 8; ++p) {
        int n = p * 8 + srow;
        *(uint4*)(wt_s + n * 256 + ((scol ^ n) & 31) * 8) = stg[p];
    }
    __syncthreads();

    for (int slab = 0; slab < 16; ++slab) {
        if (slab < 15) {
            #pragma unroll
            for (int p = 0; p < 8; ++p) {
                int n = p * 8 + srow;
                stg[p] = *(const uint4*)(WT + (size_t)(ob + n) * KTOT + (slab + 1) * 256 + scol * 8);
            }
        }
        const int part  = slab >> 3;          // 0: xn * Aw, 1: 1.0 * Bw
        const int i_off = (slab & 7) * 32;    // 32 features per slab

        #pragma unroll
        for (int ch = 0; ch < 8; ++ch) {      // 8 x K32 chunks per slab
            const int i = i_off + ch * 4 + quad;   // this lane's feature
            half8 a[2], b[2];
            #pragma unroll
            for (int sm = 0; sm < 2; ++sm) {
                const int m = wm * 32 + sm * 16 + lane16;
                const uint32_t u   = meta_s[m * 257 + i];
                const uint32_t xb  = part ? 0x3C00u : (u & 0xFFFFu);  // f16 1.0 for bias
                const uint32_t seg = u >> 16;
                const uint64_t oh  = (uint64_t)xb << ((seg & 3) * 16);
                const uint64_t lo  = (seg < 4) ? oh : 0ull;
                const uint64_t hi  = (seg < 4) ? 0ull : oh;
                uintx4 w;
                w[0] = (uint32_t)lo; w[1] = (uint32_t)(lo >> 32);
                w[2] = (uint32_t)hi; w[3] = (uint32_t)(hi >> 32);
                a[sm] = __builtin_bit_cast(half8, w);
            }
            #pragma unroll
            for (int sn = 0; sn < 2; ++sn) {
                const int n    = wn * 32 + sn * 16 + lane16;
                const int cell = ((ch * 4 + quad) ^ n) & 31;
                b[sn] = *(const half8*)(wt_s + n * 256 + cell * 8);
            }
            #pragma unroll
            for (int sm = 0; sm < 2; ++sm)
                #pragma unroll
                for (int sn = 0; sn < 2; ++sn)
                    acc[sm][sn] = __builtin_amdgcn_mfma_f32_16x16x32_f16(
                        a[sm], b[sn], acc[sm][sn], 0, 0, 0);
        }
        __syncthreads();       // all reads of wt_s slab done
        if (slab < 15) {
            #pragma unroll
            for (int p = 0; p < 8; ++p) {
                int n = p * 8 + srow;
                *(uint4*)(wt_s + n * 256 + ((scol ^ n) & 31) * 8) = stg[p];
            }
            __syncthreads();
        }
    }

    // epilogue: C/D layout col=lane&15, row=quad*4+reg (verified m89/m91)
    #pragma unroll
    for (int sm = 0; sm < 2; ++sm) {
        #pragma unroll
        for (int r = 0; r < 4; ++r) {
            const int grow = rb + wm * 32 + sm * 16 + quad * 4 + r;
            if (grow < Bn) {
                #pragma unroll
                for (int sn = 0; sn < 2; ++sn) {
                    const int gcol = ob + wn * 32 + sn * 16 + lane16;
                    out[(size_t)grow * O_FEAT + gcol] = acc[sm][sn][r];
                }
            }
        }
    }
}

extern "C" void kernel_launch(void* const* d_in, const int* in_sizes, int n_in,
                              void* d_out, int out_size, void* d_ws, size_t ws_size,
                              hipStream_t stream) {
    const float* x   = (const float*)d_in[0];
    const float* Aw  = (const float*)d_in[1];
    const float* Bw  = (const float*)d_in[2];
    const float* gam = (const float*)d_in[3];
    const float* bet = (const float*)d_in[4];
    float* out       = (float*)d_out;

    unsigned short* WT = (unsigned short*)d_ws;                        // 4 MB
    uint32_t* meta_g   = (uint32_t*)((char*)d_ws + (size_t)O_FEAT * KTOT * 2); // +2 MB

    const int Bn = in_sizes[0] / I_FEAT;

    hipLaunchKernelGGL(ln_meta, dim3((Bn + 1) / 2), dim3(256), 0, stream,
                       x, gam, bet, meta_g, Bn);
    hipLaunchKernelGGL(pack_wt, dim3(O_FEAT / 64, KDIM / 64, 2), dim3(256), 0, stream,
                       Aw, Bw, WT);
    hipLaunchKernelGGL(kan_mfma, dim3(O_FEAT / 64, (Bn + 63) / 64), dim3(256), 0, stream,
                       meta_g, WT, out, Bn);
}

// Round 4
// 114.188 us; speedup vs baseline: 1.1152x; 1.1152x over previous
//
#include <hip/hip_runtime.h>

#define I_FEAT 256
#define O_FEAT 512
#define NSEG   8
#define KDIM   (I_FEAT * NSEG)   // 2048
#define KTOT   (2 * KDIM)        // 4096 (A-part || bias-part)
#define KC_N   (KTOT / 32)       // 128 K32-chunks

typedef _Float16 half8   __attribute__((ext_vector_type(8)));
typedef float    floatx4 __attribute__((ext_vector_type(4)));

// ---------------- Kernel 1: LayerNorm + segment meta ----------------
// meta[row][i] = (seg << 16) | f16bits(xn).  Block = 256 thr = 2 rows.
__global__ __launch_bounds__(256) void ln_meta(
    const float* __restrict__ x,
    const float* __restrict__ gamma,
    const float* __restrict__ beta,
    uint32_t* __restrict__ meta_g,
    int Bn)
{
    __shared__ float s_psum[4];
    __shared__ float s_psq[4];

    const int tid  = threadIdx.x;
    const int row0 = blockIdx.x * 2;
    const int wave = tid >> 6;
    const int lr   = tid >> 7;
    const int lt   = tid & 127;
    const int row  = row0 + lr;

    float v0 = 0.f, v1 = 0.f;
    if (row < Bn) {
        const float* xr = x + (size_t)row * I_FEAT;
        v0 = xr[lt];
        v1 = xr[lt + 128];
    }
    float sum = v0 + v1;
    float sq  = v0 * v0 + v1 * v1;
    #pragma unroll
    for (int d = 32; d > 0; d >>= 1) {
        sum += __shfl_down(sum, d);
        sq  += __shfl_down(sq, d);
    }
    if ((tid & 63) == 0) { s_psum[wave] = sum; s_psq[wave] = sq; }
    __syncthreads();
    if (row >= Bn) return;

    const float fsum = s_psum[2 * lr] + s_psum[2 * lr + 1];
    const float fsq  = s_psq[2 * lr]  + s_psq[2 * lr + 1];
    const float mu   = fsum * (1.0f / I_FEAT);
    const float var  = fsq * (1.0f / I_FEAT) - mu * mu;
    const float rs   = rsqrtf(var + 1e-5f);

    uint32_t* mr = meta_g + (size_t)row * I_FEAT;
    #pragma unroll
    for (int h = 0; h < 2; ++h) {
        const int f = lt + h * 128;
        const float v = h ? v1 : v0;
        float xn = (v - mu) * rs * gamma[f] + beta[f];
        float fi = (xn + 1.0f) * 4.0f;     // (xn - GRID_MIN)/STEP, exact in fp32
        int seg = (int)fi;                  // trunc == jnp astype(int32)
        seg = seg < 0 ? 0 : (seg > NSEG - 1 ? NSEG - 1 : seg);
        _Float16 hx = (_Float16)xn;
        uint32_t hb = (uint32_t)__builtin_bit_cast(unsigned short, hx);
        mr[f] = ((uint32_t)seg << 16) | hb;
    }
}

// ---------------- Kernel 2: weights -> B-fragment stream ----------------
// Bf frag index ((n16t*128 + kc)*64 + lane): lane holds 8 f16 =
// W[k = kc*32 + quad*8 + j][n = n16t*16 + lane16], W[k][o] = k<2048 ? Aw : Bw.
// Exactly the mfma_f32_16x16x32_f16 B-operand layout, in wave-load order.
__global__ __launch_bounds__(256) void pack_bfrag(
    const float* __restrict__ Aw,
    const float* __restrict__ Bw,
    uint4* __restrict__ Bf)
{
    __shared__ unsigned short T[64][72];   // [n][k] f16, padded
    const int t  = threadIdx.x;
    const int n0 = blockIdx.x * 64;
    const int k0 = blockIdx.y * 64;
    const float* src = (k0 < KDIM) ? (Aw + (size_t)k0 * O_FEAT)
                                   : (Bw + (size_t)(k0 - KDIM) * O_FEAT);

    // phase 1: 64k x 64n fp32 tile -> f16, transposed into T[n][k]
    #pragma unroll
    for (int s = 0; s < 4; ++s) {
        int e  = s * 1024 + t * 4;
        int kl = e >> 6, nl = e & 63;
        const float4 v = *(const float4*)(src + (size_t)kl * O_FEAT + n0 + nl);
        T[nl + 0][kl] = __builtin_bit_cast(unsigned short, (_Float16)v.x);
        T[nl + 1][kl] = __builtin_bit_cast(unsigned short, (_Float16)v.y);
        T[nl + 2][kl] = __builtin_bit_cast(unsigned short, (_Float16)v.z);
        T[nl + 3][kl] = __builtin_bit_cast(unsigned short, (_Float16)v.w);
    }
    __syncthreads();

    // phase 2: emit frags (coalesced 16B per lane)
    const int lane = t & 63, lane16 = lane & 15, quad = lane >> 4;
    const int sub  = t >> 6;
    #pragma unroll
    for (int f = 0; f < 2; ++f) {
        const int combo = sub * 2 + f;       // 0..7
        const int n16g  = combo & 3;
        const int kch   = combo >> 2;
        const int nl = n16g * 16 + lane16;
        const int kl = kch * 32 + quad * 8;
        const uint4 val = *(const uint4*)&T[nl][kl];   // 16B aligned
        const int n16t = (n0 >> 4) + n16g;
        const int kc   = (k0 >> 5) + kch;
        Bf[((size_t)n16t * KC_N + kc) * 64 + lane] = val;
    }
}

// ---------------- Kernel 3: meta -> one-hot A-fragment stream ----------------
// Af frag index ((mt16*128 + kc)*64 + lane): lane holds 8 f16 one-hot window
// for m = mt16*16 + lane16, window w = kc*4 + quad (w<256: xn one-hot at seg;
// w>=256: f16(1.0) one-hot at seg -> bias part).
__global__ __launch_bounds__(256) void expand_afrag(
    const uint32_t* __restrict__ meta_g,
    uint4* __restrict__ Af,
    int Bn, int mt16Tot)
{
    const int gid  = blockIdx.x * 256 + threadIdx.x;
    const int lane = gid & 63;
    const int fc   = gid >> 6;
    const int kc   = fc & (KC_N - 1);
    const int mt16 = fc >> 7;
    if (mt16 >= mt16Tot) return;

    const int m = mt16 * 16 + (lane & 15);
    const int w = kc * 4 + (lane >> 4);
    const int part = w >> 8;
    const int i = w & 255;

    uint32_t u = 0;
    if (m < Bn) u = meta_g[(size_t)m * I_FEAT + i];

    const uint32_t xb  = part ? ((m < Bn) ? 0x3C00u : 0u) : (u & 0xFFFFu);
    const uint32_t seg = u >> 16;
    const uint64_t oh  = (uint64_t)xb << ((seg & 3) * 16);
    const uint64_t lo  = (seg < 4) ? oh : 0ull;
    const uint64_t hi  = (seg < 4) ? 0ull : oh;
    uint4 wv;
    wv.x = (uint32_t)lo; wv.y = (uint32_t)(lo >> 32);
    wv.z = (uint32_t)hi; wv.w = (uint32_t)(hi >> 32);
    Af[gid] = wv;
}

// ---------------- Kernel 4: streaming MFMA GEMM (no LDS, no barriers) ----------------
// Block 256 = 4 waves (2x2 of 32x32); K-loop: 4 coalesced dwordx4 + 4 MFMA
// per K32-chunk. bid = ot*rtTot + rt -> XCD (bid%8) owns rt = c (mod 8):
// its 2 MB A-slice stays L2-resident across all 8 ot.
__global__ __launch_bounds__(256) void kan_gemm(
    const uint4* __restrict__ Af,
    const uint4* __restrict__ Bf,
    float* __restrict__ out,
    int Bn, int rtTot)
{
    const int t    = threadIdx.x;
    const int wave = t >> 6, lane = t & 63;
    const int wm   = wave >> 1, wn = wave & 1;
    const int lane16 = lane & 15, quad = lane >> 4;

    const int bid = blockIdx.x;
    const int ot  = bid / rtTot;
    const int rt  = bid - ot * rtTot;

    const uint4* pa0 = Af + ((size_t)(rt * 4 + wm * 2 + 0) * KC_N) * 64 + lane;
    const uint4* pa1 = Af + ((size_t)(rt * 4 + wm * 2 + 1) * KC_N) * 64 + lane;
    const uint4* pb0 = Bf + ((size_t)(ot * 4 + wn * 2 + 0) * KC_N) * 64 + lane;
    const uint4* pb1 = Bf + ((size_t)(ot * 4 + wn * 2 + 1) * KC_N) * 64 + lane;

    floatx4 acc[2][2] = {};

    #pragma unroll 4
    for (int kc = 0; kc < KC_N; ++kc) {
        const half8 a0 = __builtin_bit_cast(half8, pa0[(size_t)kc * 64]);
        const half8 a1 = __builtin_bit_cast(half8, pa1[(size_t)kc * 64]);
        const half8 b0 = __builtin_bit_cast(half8, pb0[(size_t)kc * 64]);
        const half8 b1 = __builtin_bit_cast(half8, pb1[(size_t)kc * 64]);
        acc[0][0] = __builtin_amdgcn_mfma_f32_16x16x32_f16(a0, b0, acc[0][0], 0, 0, 0);
        acc[0][1] = __builtin_amdgcn_mfma_f32_16x16x32_f16(a0, b1, acc[0][1], 0, 0, 0);
        acc[1][0] = __builtin_amdgcn_mfma_f32_16x16x32_f16(a1, b0, acc[1][0], 0, 0, 0);
        acc[1][1] = __builtin_amdgcn_mfma_f32_16x16x32_f16(a1, b1, acc[1][1], 0, 0, 0);
    }

    // epilogue: C/D layout col=lane&15, row=quad*4+reg (verified R3)
    const int rb = rt * 64;
    const int ob = ot * 64;
    #pragma unroll
    for (int sm = 0; sm < 2; ++sm) {
        #pragma unroll
        for (int r = 0; r < 4; ++r) {
            const int grow = rb + wm * 32 + sm * 16 + quad * 4 + r;
            if (grow < Bn) {
                #pragma unroll
                for (int sn = 0; sn < 2; ++sn) {
                    const int gcol = ob + wn * 32 + sn * 16 + lane16;
                    out[(size_t)grow * O_FEAT + gcol] = acc[sm][sn][r];
                }
            }
        }
    }
}

extern "C" void kernel_launch(void* const* d_in, const int* in_sizes, int n_in,
                              void* d_out, int out_size, void* d_ws, size_t ws_size,
                              hipStream_t stream) {
    const float* x   = (const float*)d_in[0];
    const float* Aw  = (const float*)d_in[1];
    const float* Bw  = (const float*)d_in[2];
    const float* gam = (const float*)d_in[3];
    const float* bet = (const float*)d_in[4];
    float* out       = (float*)d_out;

    const int Bn      = in_sizes[0] / I_FEAT;
    const int rtTot   = (Bn + 63) / 64;
    const int mt16Tot = rtTot * 4;

    // ws layout: Bf 4MB | Af (mt16Tot*128*64*16B) | meta (Bn*256*4B)
    uint4* Bf        = (uint4*)d_ws;
    uint4* Af        = Bf + (size_t)(O_FEAT / 16) * KC_N * 64;
    uint32_t* meta_g = (uint32_t*)(Af + (size_t)mt16Tot * KC_N * 64);

    hipLaunchKernelGGL(ln_meta, dim3((Bn + 1) / 2), dim3(256), 0, stream,
                       x, gam, bet, meta_g, Bn);
    hipLaunchKernelGGL(pack_bfrag, dim3(O_FEAT / 64, KTOT / 64), dim3(256), 0, stream,
                       Aw, Bw, Bf);
    const int nAfrag = mt16Tot * KC_N * 64;
    hipLaunchKernelGGL(expand_afrag, dim3((nAfrag + 255) / 256), dim3(256), 0, stream,
                       meta_g, Af, Bn, mt16Tot);
    hipLaunchKernelGGL(kan_gemm, dim3((O_FEAT / 64) * rtTot), dim3(256), 0, stream,
                       Af, Bf, out, Bn, rtTot);
}

// Round 5
// 91.376 us; speedup vs baseline: 1.3936x; 1.2497x over previous
//
#include <hip/hip_runtime.h>

#define I_FEAT 256
#define O_FEAT 512
#define NSEG   8
#define KDIM   (I_FEAT * NSEG)   // 2048
#define KTOT   (2 * KDIM)        // 4096 (A-part || bias-part)
#define KC_N   (KTOT / 32)       // 128 K32-chunks

typedef _Float16 half8   __attribute__((ext_vector_type(8)));
typedef float    floatx4 __attribute__((ext_vector_type(4)));
typedef uint32_t uintx4  __attribute__((ext_vector_type(4)));

// ---------------- Kernel 1: LayerNorm + segment meta ----------------
// meta[row][i] = (seg << 16) | f16bits(xn).  Block = 256 thr = 2 rows.
__global__ __launch_bounds__(256) void ln_meta(
    const float* __restrict__ x,
    const float* __restrict__ gamma,
    const float* __restrict__ beta,
    uint32_t* __restrict__ meta_g,
    int Bn)
{
    __shared__ float s_psum[4];
    __shared__ float s_psq[4];

    const int tid  = threadIdx.x;
    const int row0 = blockIdx.x * 2;
    const int wave = tid >> 6;
    const int lr   = tid >> 7;
    const int lt   = tid & 127;
    const int row  = row0 + lr;

    float v0 = 0.f, v1 = 0.f;
    if (row < Bn) {
        const float* xr = x + (size_t)row * I_FEAT;
        v0 = xr[lt];
        v1 = xr[lt + 128];
    }
    float sum = v0 + v1;
    float sq  = v0 * v0 + v1 * v1;
    #pragma unroll
    for (int d = 32; d > 0; d >>= 1) {
        sum += __shfl_down(sum, d);
        sq  += __shfl_down(sq, d);
    }
    if ((tid & 63) == 0) { s_psum[wave] = sum; s_psq[wave] = sq; }
    __syncthreads();
    if (row >= Bn) return;

    const float fsum = s_psum[2 * lr] + s_psum[2 * lr + 1];
    const float fsq  = s_psq[2 * lr]  + s_psq[2 * lr + 1];
    const float mu   = fsum * (1.0f / I_FEAT);
    const float var  = fsq * (1.0f / I_FEAT) - mu * mu;
    const float rs   = rsqrtf(var + 1e-5f);

    uint32_t* mr = meta_g + (size_t)row * I_FEAT;
    #pragma unroll
    for (int h = 0; h < 2; ++h) {
        const int f = lt + h * 128;
        const float v = h ? v1 : v0;
        float xn = (v - mu) * rs * gamma[f] + beta[f];
        float fi = (xn + 1.0f) * 4.0f;     // (xn - GRID_MIN)/STEP, exact in fp32
        int seg = (int)fi;                  // trunc == jnp astype(int32)
        seg = seg < 0 ? 0 : (seg > NSEG - 1 ? NSEG - 1 : seg);
        _Float16 hx = (_Float16)xn;
        uint32_t hb = (uint32_t)__builtin_bit_cast(unsigned short, hx);
        mr[f] = ((uint32_t)seg << 16) | hb;
    }
}

// ---------------- Kernel 2: weights -> B-fragment stream ----------------
// Bf frag index ((n16t*128 + kc)*64 + lane): lane holds 8 f16 =
// W[k = kc*32 + quad*8 + j][n = n16t*16 + lane16], W[k][o] = k<2048 ? Aw : Bw.
__global__ __launch_bounds__(256) void pack_bfrag(
    const float* __restrict__ Aw,
    const float* __restrict__ Bw,
    uint4* __restrict__ Bf)
{
    __shared__ unsigned short T[64][72];   // [n][k] f16, padded
    const int t  = threadIdx.x;
    const int n0 = blockIdx.x * 64;
    const int k0 = blockIdx.y * 64;
    const float* src = (k0 < KDIM) ? (Aw + (size_t)k0 * O_FEAT)
                                   : (Bw + (size_t)(k0 - KDIM) * O_FEAT);

    #pragma unroll
    for (int s = 0; s < 4; ++s) {
        int e  = s * 1024 + t * 4;
        int kl = e >> 6, nl = e & 63;
        const float4 v = *(const float4*)(src + (size_t)kl * O_FEAT + n0 + nl);
        T[nl + 0][kl] = __builtin_bit_cast(unsigned short, (_Float16)v.x);
        T[nl + 1][kl] = __builtin_bit_cast(unsigned short, (_Float16)v.y);
        T[nl + 2][kl] = __builtin_bit_cast(unsigned short, (_Float16)v.z);
        T[nl + 3][kl] = __builtin_bit_cast(unsigned short, (_Float16)v.w);
    }
    __syncthreads();

    const int lane = t & 63, lane16 = lane & 15, quad = lane >> 4;
    const int sub  = t >> 6;
    #pragma unroll
    for (int f = 0; f < 2; ++f) {
        const int combo = sub * 2 + f;       // 0..7
        const int n16g  = combo & 3;
        const int kch   = combo >> 2;
        const int nl = n16g * 16 + lane16;
        const int kl = kch * 32 + quad * 8;
        const uint4 val = *(const uint4*)&T[nl][kl];
        const int n16t = (n0 >> 4) + n16g;
        const int kc   = (k0 >> 5) + kch;
        Bf[((size_t)n16t * KC_N + kc) * 64 + lane] = val;
    }
}

// ---------------- Kernel 3: meta -> A-meta stream (4B per fragment-lane) ----------------
// Am[(mt16*64 + kcp)*64 + lane] = uint2 { word(kc=2kcp), word(kc=2kcp+1) }
// word for (m = mt16*16+lane16, w = kc*4+quad): w<256 -> meta (seg<<16 | f16(xn));
// w>=256 -> (seg<<16 | f16(1.0))  => uniform decode in the GEMM.
__global__ __launch_bounds__(256) void am_pack(
    const uint32_t* __restrict__ meta_g,
    uint2* __restrict__ Am,
    int Bn, int mt16Tot)
{
    const int gid  = blockIdx.x * 256 + threadIdx.x;
    const int lane = gid & 63;
    const int pc   = gid >> 6;        // mt16*64 + kcp
    const int kcp  = pc & 63;
    const int mt16 = pc >> 6;
    if (mt16 >= mt16Tot) return;
    const int m    = mt16 * 16 + (lane & 15);
    const int quad = lane >> 4;

    uint2 v = make_uint2(0u, 0u);
    if (m < Bn) {
        const uint32_t* mr = meta_g + (size_t)m * I_FEAT;
        #pragma unroll
        for (int h = 0; h < 2; ++h) {
            const int w    = (kcp * 2 + h) * 4 + quad;
            const int part = w >> 8;
            const int i    = w & 255;
            const uint32_t u = mr[i];
            const uint32_t val = part ? ((u & 0xFFFF0000u) | 0x3C00u) : u;
            if (h == 0) v.x = val; else v.y = val;
        }
    }
    Am[gid] = v;
}

// ---------------- Kernel 4: streaming MFMA GEMM, in-register one-hot A ----------------
// Block 256 = 4 waves, tile 32m x 32n, 4-way kc split across waves + LDS reduce.
// Grid 16(ot) x 64(rt) = 1024 blocks = 4 blocks/CU = 4 waves/SIMD.
static __device__ __forceinline__ half8 build_onehot(uint32_t u) {
    const uint32_t xb  = u & 0xFFFFu;
    const uint32_t seg = u >> 16;
    const uint64_t oh  = (uint64_t)xb << ((seg & 3u) << 4);
    const uint64_t lo  = (seg < 4u) ? oh : 0ull;
    const uint64_t hi  = (seg < 4u) ? 0ull : oh;
    uintx4 w;
    w[0] = (uint32_t)lo; w[1] = (uint32_t)(lo >> 32);
    w[2] = (uint32_t)hi; w[3] = (uint32_t)(hi >> 32);
    return __builtin_bit_cast(half8, w);
}

__global__ __launch_bounds__(256, 4) void kan_gemm(
    const uint2* __restrict__ Am,
    const uint4* __restrict__ Bf,
    float* __restrict__ out,
    int Bn)
{
    __shared__ float s_red[3][16][64];

    const int t      = threadIdx.x;
    const int wave   = t >> 6, lane = t & 63;
    const int lane16 = lane & 15, quad = lane >> 4;
    const int bid    = blockIdx.x;
    const int ot     = bid & 15;      // n-tile of 32 -> XCD sees 2 ot slices (L2-resident Bf)
    const int rt     = bid >> 4;      // m-tile of 32

    const uint2* pa0 = Am + ((size_t)(rt * 2 + 0) * 64) * 64 + lane;
    const uint2* pa1 = Am + ((size_t)(rt * 2 + 1) * 64) * 64 + lane;
    const uint4* pb0 = Bf + ((size_t)(ot * 2 + 0) * KC_N) * 64 + lane;
    const uint4* pb1 = Bf + ((size_t)(ot * 2 + 1) * KC_N) * 64 + lane;

    floatx4 acc[2][2] = {};
    const int kcp0 = wave * 16;       // 16 kc-pairs = 32 kc per wave

    #pragma unroll 4
    for (int p = 0; p < 16; ++p) {
        const int kcp = kcp0 + p;
        const uint2 u0   = pa0[(size_t)kcp * 64];
        const uint2 u1   = pa1[(size_t)kcp * 64];
        const uint4 bv00 = pb0[(size_t)(2 * kcp + 0) * 64];
        const uint4 bv01 = pb0[(size_t)(2 * kcp + 1) * 64];
        const uint4 bv10 = pb1[(size_t)(2 * kcp + 0) * 64];
        const uint4 bv11 = pb1[(size_t)(2 * kcp + 1) * 64];
        {   // kc = 2*kcp
            const half8 a0 = build_onehot(u0.x);
            const half8 a1 = build_onehot(u1.x);
            const half8 b0 = __builtin_bit_cast(half8, bv00);
            const half8 b1 = __builtin_bit_cast(half8, bv10);
            acc[0][0] = __builtin_amdgcn_mfma_f32_16x16x32_f16(a0, b0, acc[0][0], 0, 0, 0);
            acc[0][1] = __builtin_amdgcn_mfma_f32_16x16x32_f16(a0, b1, acc[0][1], 0, 0, 0);
            acc[1][0] = __builtin_amdgcn_mfma_f32_16x16x32_f16(a1, b0, acc[1][0], 0, 0, 0);
            acc[1][1] = __builtin_amdgcn_mfma_f32_16x16x32_f16(a1, b1, acc[1][1], 0, 0, 0);
        }
        {   // kc = 2*kcp + 1
            const half8 a0 = build_onehot(u0.y);
            const half8 a1 = build_onehot(u1.y);
            const half8 b0 = __builtin_bit_cast(half8, bv01);
            const half8 b1 = __builtin_bit_cast(half8, bv11);
            acc[0][0] = __builtin_amdgcn_mfma_f32_16x16x32_f16(a0, b0, acc[0][0], 0, 0, 0);
            acc[0][1] = __builtin_amdgcn_mfma_f32_16x16x32_f16(a0, b1, acc[0][1], 0, 0, 0);
            acc[1][0] = __builtin_amdgcn_mfma_f32_16x16x32_f16(a1, b0, acc[1][0], 0, 0, 0);
            acc[1][1] = __builtin_amdgcn_mfma_f32_16x16x32_f16(a1, b1, acc[1][1], 0, 0, 0);
        }
    }

    // cross-wave kc reduction: waves 1..3 dump partials, wave 0 adds + stores.
    if (wave != 0) {
        #pragma unroll
        for (int sm = 0; sm < 2; ++sm)
            #pragma unroll
            for (int sn = 0; sn < 2; ++sn)
                #pragma unroll
                for (int r = 0; r < 4; ++r)
                    s_red[wave - 1][(sm * 2 + sn) * 4 + r][lane] = acc[sm][sn][r];
    }
    __syncthreads();
    if (wave == 0) {
        #pragma unroll
        for (int sm = 0; sm < 2; ++sm) {
            #pragma unroll
            for (int sn = 0; sn < 2; ++sn) {
                #pragma unroll
                for (int r = 0; r < 4; ++r) {
                    const int idx = (sm * 2 + sn) * 4 + r;
                    const float v = acc[sm][sn][r]
                                  + s_red[0][idx][lane]
                                  + s_red[1][idx][lane]
                                  + s_red[2][idx][lane];
                    const int grow = rt * 32 + sm * 16 + quad * 4 + r;
                    const int gcol = ot * 32 + sn * 16 + lane16;
                    if (grow < Bn)
                        out[(size_t)grow * O_FEAT + gcol] = v;
                }
            }
        }
    }
}

extern "C" void kernel_launch(void* const* d_in, const int* in_sizes, int n_in,
                              void* d_out, int out_size, void* d_ws, size_t ws_size,
                              hipStream_t stream) {
    const float* x   = (const float*)d_in[0];
    const float* Aw  = (const float*)d_in[1];
    const float* Bw  = (const float*)d_in[2];
    const float* gam = (const float*)d_in[3];
    const float* bet = (const float*)d_in[4];
    float* out       = (float*)d_out;

    const int Bn       = in_sizes[0] / I_FEAT;
    const int rt32Tot  = (Bn + 31) / 32;
    const int mt16Tot  = rt32Tot * 2;

    // ws: Bf 4MB | Am (mt16Tot*64*64*8B) | meta (Bn*256*4B)
    uint4* Bf        = (uint4*)d_ws;
    uint2* Am        = (uint2*)(Bf + (size_t)(O_FEAT / 16) * KC_N * 64);
    uint32_t* meta_g = (uint32_t*)(Am + (size_t)mt16Tot * 64 * 64);

    hipLaunchKernelGGL(ln_meta, dim3((Bn + 1) / 2), dim3(256), 0, stream,
                       x, gam, bet, meta_g, Bn);
    hipLaunchKernelGGL(pack_bfrag, dim3(O_FEAT / 64, KTOT / 64), dim3(256), 0, stream,
                       Aw, Bw, Bf);
    hipLaunchKernelGGL(am_pack, dim3(mt16Tot * 16), dim3(256), 0, stream,
                       meta_g, Am, Bn, mt16Tot);
    hipLaunchKernelGGL(kan_gemm, dim3(16 * rt32Tot), dim3(256), 0, stream,
                       Am, Bf, out, Bn);
}

// Round 6
// 87.818 us; speedup vs baseline: 1.4501x; 1.0405x over previous
//
#include <hip/hip_runtime.h>

#define I_FEAT 256
#define O_FEAT 512
#define NSEG   8
#define KDIM   (I_FEAT * NSEG)   // 2048
#define KTOT   (2 * KDIM)        // 4096 (A-part || bias-part)
#define KC_N   (KTOT / 32)       // 128 K32-chunks

typedef _Float16 half8   __attribute__((ext_vector_type(8)));
typedef float    floatx4 __attribute__((ext_vector_type(4)));
typedef uint32_t uintx4  __attribute__((ext_vector_type(4)));

// ---------------- Kernel 1: prep (pack_bfrag ∪ fused LN->Am), bid-split ----------------
// bid < 512: pack one 64n x 64k weight tile into B-fragment stream Bf.
// bid >= 512: LN + segment meta for one mt16 (16 rows), emit A-meta stream Am.
__global__ __launch_bounds__(256) void prep(
    const float* __restrict__ x,
    const float* __restrict__ Aw,
    const float* __restrict__ Bw,
    const float* __restrict__ gamma,
    const float* __restrict__ beta,
    uint4* __restrict__ Bf,
    uint2* __restrict__ Am,
    int Bn, int pbTot)
{
    __shared__ char smem[16 * 260 * 4];   // 16640 B, reused by both paths
    const int t   = threadIdx.x;
    const int bid = blockIdx.x;

    if (bid < pbTot) {
        // ---- weight pack path ----
        unsigned short (*T)[72] = (unsigned short(*)[72])smem;  // [n][k] f16
        const int n0 = (bid & 7) * 64;
        const int k0 = (bid >> 3) * 64;
        const float* src = (k0 < KDIM) ? (Aw + (size_t)k0 * O_FEAT)
                                       : (Bw + (size_t)(k0 - KDIM) * O_FEAT);
        #pragma unroll
        for (int s = 0; s < 4; ++s) {
            int e  = s * 1024 + t * 4;
            int kl = e >> 6, nl = e & 63;
            const float4 v = *(const float4*)(src + (size_t)kl * O_FEAT + n0 + nl);
            T[nl + 0][kl] = __builtin_bit_cast(unsigned short, (_Float16)v.x);
            T[nl + 1][kl] = __builtin_bit_cast(unsigned short, (_Float16)v.y);
            T[nl + 2][kl] = __builtin_bit_cast(unsigned short, (_Float16)v.z);
            T[nl + 3][kl] = __builtin_bit_cast(unsigned short, (_Float16)v.w);
        }
        __syncthreads();

        const int lane = t & 63, lane16 = lane & 15, quad = lane >> 4;
        const int sub  = t >> 6;
        #pragma unroll
        for (int f = 0; f < 2; ++f) {
            const int combo = sub * 2 + f;       // 0..7
            const int n16g  = combo & 3;
            const int kch   = combo >> 2;
            const int nl = n16g * 16 + lane16;
            const int kl = kch * 32 + quad * 8;
            const uint4 val = *(const uint4*)&T[nl][kl];
            const int n16t = (n0 >> 4) + n16g;
            const int kc   = (k0 >> 5) + kch;
            Bf[((size_t)n16t * KC_N + kc) * 64 + lane] = val;
        }
    } else {
        // ---- LN -> Am path: one mt16 (16 rows), 16 threads per row ----
        uint32_t (*M)[260] = (uint32_t(*)[260])smem;   // [row][feat], pad 260 (2-way max)
        const int mt16 = bid - pbTot;
        const int rr   = t >> 4;         // row within tile
        const int c16  = t & 15;         // 16-col group
        const int row  = mt16 * 16 + rr;
        const bool ok  = (row < Bn);

        float4 v[4];
        const float* xr = x + (size_t)row * I_FEAT + c16 * 16;
        #pragma unroll
        for (int j = 0; j < 4; ++j)
            v[j] = ok ? *(const float4*)(xr + j * 4) : make_float4(0.f, 0.f, 0.f, 0.f);

        float sum = 0.f, sq = 0.f;
        #pragma unroll
        for (int j = 0; j < 4; ++j) {
            sum += v[j].x + v[j].y + v[j].z + v[j].w;
            sq  += v[j].x * v[j].x + v[j].y * v[j].y
                 + v[j].z * v[j].z + v[j].w * v[j].w;
        }
        #pragma unroll
        for (int mask = 1; mask < 16; mask <<= 1) {   // 16-lane group reduce
            sum += __shfl_xor(sum, mask);
            sq  += __shfl_xor(sq,  mask);
        }
        const float mu  = sum * (1.0f / I_FEAT);
        const float var = sq * (1.0f / I_FEAT) - mu * mu;
        const float rs  = rsqrtf(var + 1e-5f);

        #pragma unroll
        for (int j = 0; j < 4; ++j) {
            const float4 g4 = *(const float4*)(gamma + c16 * 16 + j * 4);
            const float4 b4 = *(const float4*)(beta  + c16 * 16 + j * 4);
            const float vv[4] = { v[j].x, v[j].y, v[j].z, v[j].w };
            const float gg[4] = { g4.x, g4.y, g4.z, g4.w };
            const float bb[4] = { b4.x, b4.y, b4.z, b4.w };
            #pragma unroll
            for (int e = 0; e < 4; ++e) {
                const int c = c16 * 16 + j * 4 + e;
                float xn = (vv[e] - mu) * rs * gg[e] + bb[e];
                float fi = (xn + 1.0f) * 4.0f;   // (xn - GRID_MIN)/STEP, exact fp32
                int seg = (int)fi;                // trunc == jnp astype(int32)
                seg = seg < 0 ? 0 : (seg > NSEG - 1 ? NSEG - 1 : seg);
                _Float16 hx = (_Float16)xn;
                M[rr][c] = ((uint32_t)seg << 16)
                         | (uint32_t)__builtin_bit_cast(unsigned short, hx);
            }
        }
        __syncthreads();

        // emit Am: word(m,w): w<256 -> meta; w>=256 -> (seg<<16 | f16(1.0))
        const int lane = t & 63, g = t >> 6;
        const int m_local = lane & 15, quad = lane >> 4;
        uint2* dst = Am + (size_t)mt16 * 64 * 64 + lane;
        #pragma unroll
        for (int kk = 0; kk < 16; ++kk) {
            const int kcp = g * 16 + kk;
            const int w0  = kcp * 8 + quad;        // h=0: (kcp*2)*4+quad
            const int w1  = w0 + 4;                // h=1
            const uint32_t u0 = M[m_local][w0 & 255];
            const uint32_t u1 = M[m_local][w1 & 255];
            const uint32_t a  = (w0 >> 8) ? ((u0 & 0xFFFF0000u) | 0x3C00u) : u0;
            const uint32_t b  = (w1 >> 8) ? ((u1 & 0xFFFF0000u) | 0x3C00u) : u1;
            dst[(size_t)kcp * 64] = make_uint2(a, b);
        }
    }
}

// ---------------- Kernel 2: streaming MFMA GEMM, 64m x 32n, k-split-4 ----------------
static __device__ __forceinline__ half8 build_onehot(uint32_t u) {
    const uint32_t xb  = u & 0xFFFFu;
    const uint32_t seg = u >> 16;
    const uint64_t oh  = (uint64_t)xb << ((seg & 3u) << 4);
    const uint64_t lo  = (seg < 4u) ? oh : 0ull;
    const uint64_t hi  = (seg < 4u) ? 0ull : oh;
    uintx4 w;
    w[0] = (uint32_t)lo; w[1] = (uint32_t)(lo >> 32);
    w[2] = (uint32_t)hi; w[3] = (uint32_t)(hi >> 32);
    return __builtin_bit_cast(half8, w);
}

__global__ __launch_bounds__(256, 2) void kan_gemm(
    const uint2* __restrict__ Am,
    const uint4* __restrict__ Bf,
    float* __restrict__ out,
    int Bn, int rt64Tot)
{
    __shared__ floatx4 s_red[4][8][64];   // 32 KB

    const int t      = threadIdx.x;
    const int wave   = t >> 6, lane = t & 63;
    const int lane16 = lane & 15, quad = lane >> 4;
    const int bid    = blockIdx.x;

    int ot, rt;
    if (rt64Tot == 32) {
        // XCD-aware decode (XCD = bid%8): per XCD 4 ot (1MB Bf) x 16 rt (2MB Am) = 3MB < L2
        const int xc = bid & 7, j = bid >> 3;
        ot = ((j >> 4) << 2) | (xc & 3);
        rt = (j & 15) | ((xc >> 2) << 4);
    } else {
        ot = bid & 15;
        rt = bid >> 4;
    }

    const uint2* pa = Am + (size_t)(rt * 4) * 64 * 64 + lane;     // 4 mt16 streams
    const uint4* pb = Bf + (size_t)(ot * 2) * KC_N * 64 + lane;   // 2 n16t streams

    floatx4 acc[4][2] = {};
    const int kcp0 = wave * 16;   // 4-way kc split

    #pragma unroll 4
    for (int p = 0; p < 16; ++p) {
        const int kcp = kcp0 + p;
        const uint2 u0 = pa[(size_t)kcp * 64];
        const uint2 u1 = pa[(size_t)(4096  + kcp * 64)];
        const uint2 u2 = pa[(size_t)(8192  + kcp * 64)];
        const uint2 u3 = pa[(size_t)(12288 + kcp * 64)];
        const uint4 b00 = pb[(size_t)(2 * kcp + 0) * 64];
        const uint4 b01 = pb[(size_t)(2 * kcp + 1) * 64];
        const uint4 b10 = pb[(size_t)(8192 + (2 * kcp + 0) * 64)];
        const uint4 b11 = pb[(size_t)(8192 + (2 * kcp + 1) * 64)];
        {   // kc = 2*kcp
            const half8 n0 = __builtin_bit_cast(half8, b00);
            const half8 n1 = __builtin_bit_cast(half8, b10);
            half8 a;
            a = build_onehot(u0.x);
            acc[0][0] = __builtin_amdgcn_mfma_f32_16x16x32_f16(a, n0, acc[0][0], 0, 0, 0);
            acc[0][1] = __builtin_amdgcn_mfma_f32_16x16x32_f16(a, n1, acc[0][1], 0, 0, 0);
            a = build_onehot(u1.x);
            acc[1][0] = __builtin_amdgcn_mfma_f32_16x16x32_f16(a, n0, acc[1][0], 0, 0, 0);
            acc[1][1] = __builtin_amdgcn_mfma_f32_16x16x32_f16(a, n1, acc[1][1], 0, 0, 0);
            a = build_onehot(u2.x);
            acc[2][0] = __builtin_amdgcn_mfma_f32_16x16x32_f16(a, n0, acc[2][0], 0, 0, 0);
            acc[2][1] = __builtin_amdgcn_mfma_f32_16x16x32_f16(a, n1, acc[2][1], 0, 0, 0);
            a = build_onehot(u3.x);
            acc[3][0] = __builtin_amdgcn_mfma_f32_16x16x32_f16(a, n0, acc[3][0], 0, 0, 0);
            acc[3][1] = __builtin_amdgcn_mfma_f32_16x16x32_f16(a, n1, acc[3][1], 0, 0, 0);
        }
        {   // kc = 2*kcp + 1
            const half8 n0 = __builtin_bit_cast(half8, b01);
            const half8 n1 = __builtin_bit_cast(half8, b11);
            half8 a;
            a = build_onehot(u0.y);
            acc[0][0] = __builtin_amdgcn_mfma_f32_16x16x32_f16(a, n0, acc[0][0], 0, 0, 0);
            acc[0][1] = __builtin_amdgcn_mfma_f32_16x16x32_f16(a, n1, acc[0][1], 0, 0, 0);
            a = build_onehot(u1.y);
            acc[1][0] = __builtin_amdgcn_mfma_f32_16x16x32_f16(a, n0, acc[1][0], 0, 0, 0);
            acc[1][1] = __builtin_amdgcn_mfma_f32_16x16x32_f16(a, n1, acc[1][1], 0, 0, 0);
            a = build_onehot(u2.y);
            acc[2][0] = __builtin_amdgcn_mfma_f32_16x16x32_f16(a, n0, acc[2][0], 0, 0, 0);
            acc[2][1] = __builtin_amdgcn_mfma_f32_16x16x32_f16(a, n1, acc[2][1], 0, 0, 0);
            a = build_onehot(u3.y);
            acc[3][0] = __builtin_amdgcn_mfma_f32_16x16x32_f16(a, n0, acc[3][0], 0, 0, 0);
            acc[3][1] = __builtin_amdgcn_mfma_f32_16x16x32_f16(a, n1, acc[3][1], 0, 0, 0);
        }
    }

    // cross-wave kc reduction: every wave dumps all 8 tiles, then sums 2 tiles.
    #pragma unroll
    for (int mi = 0; mi < 4; ++mi)
        #pragma unroll
        for (int ni = 0; ni < 2; ++ni)
            s_red[wave][mi * 2 + ni][lane] = acc[mi][ni];
    __syncthreads();

    #pragma unroll
    for (int q = 0; q < 2; ++q) {
        const int tt = wave * 2 + q;
        const int mi = tt >> 1, ni = tt & 1;
        floatx4 vsum = s_red[0][tt][lane];
        vsum += s_red[1][tt][lane];
        vsum += s_red[2][tt][lane];
        vsum += s_red[3][tt][lane];
        const int gcol = ot * 32 + ni * 16 + lane16;
        const int gr0  = rt * 64 + mi * 16 + quad * 4;
        #pragma unroll
        for (int r = 0; r < 4; ++r) {
            const int grow = gr0 + r;
            if (grow < Bn)
                out[(size_t)grow * O_FEAT + gcol] = vsum[r];
        }
    }
}

extern "C" void kernel_launch(void* const* d_in, const int* in_sizes, int n_in,
                              void* d_out, int out_size, void* d_ws, size_t ws_size,
                              hipStream_t stream) {
    const float* x   = (const float*)d_in[0];
    const float* Aw  = (const float*)d_in[1];
    const float* Bw  = (const float*)d_in[2];
    const float* gam = (const float*)d_in[3];
    const float* bet = (const float*)d_in[4];
    float* out       = (float*)d_out;

    const int Bn      = in_sizes[0] / I_FEAT;
    const int mt16Tot = (Bn + 15) / 16;
    const int rt64Tot = (Bn + 63) / 64;
    const int pbTot   = (O_FEAT / 64) * (KTOT / 64);   // 512

    // ws: Bf 4MB | Am (mt16Tot*64*64*8B)
    uint4* Bf = (uint4*)d_ws;
    uint2* Am = (uint2*)(Bf + (size_t)(O_FEAT / 16) * KC_N * 64);

    hipLaunchKernelGGL(prep, dim3(pbTot + mt16Tot), dim3(256), 0, stream,
                       x, Aw, Bw, gam, bet, Bf, Am, Bn, pbTot);
    hipLaunchKernelGGL(kan_gemm, dim3(16 * rt64Tot), dim3(256), 0, stream,
                       Am, Bf, out, Bn, rt64Tot);
}